// Round 1
// baseline (2994.229 us; speedup 1.0000x reference)
//
#include <hip/hip_runtime.h>
#include <stdint.h>

// ---------------- problem constants ----------------
constexpr int Lc  = 197;
constexpr int Nc  = 128;
constexpr int Ec  = 768;
constexpr int Hc  = 12;
constexpr int HDc = 64;
constexpr int Bc  = Nc * Hc;        // 1536 batch*heads
constexpr int NSc = 60;
constexpr int LTc = Lc + NSc;       // 257 output rows
constexpr float EPSc = 1e-12f;
constexpr uint32_t RSZc = 60u * 1536u * 197u;  // 18,155,520 uniforms for r

// JAX threefry variant: 1 = jax_threefry_partitionable (default since JAX 0.5)
// 0 = legacy "original" random_bits / split. Flip to 0 if absmax ~0.1-0.3.
#define TF_PARTITIONABLE 1

// ---------------- threefry2x32 (JAX-exact) ----------------
struct U2 { uint32_t x, y; };

__device__ __forceinline__ U2 tf2x32(uint32_t k0, uint32_t k1, uint32_t x0, uint32_t x1) {
  uint32_t k2 = k0 ^ k1 ^ 0x1BD11BDAu;
  x0 += k0; x1 += k1;
#define TFR(r) { x0 += x1; x1 = (x1 << (r)) | (x1 >> (32 - (r))); x1 ^= x0; }
  TFR(13) TFR(15) TFR(26) TFR(6)
  x0 += k1; x1 += k2 + 1u;
  TFR(17) TFR(29) TFR(16) TFR(24)
  x0 += k2; x1 += k0 + 2u;
  TFR(13) TFR(15) TFR(26) TFR(6)
  x0 += k0; x1 += k1 + 3u;
  TFR(17) TFR(29) TFR(16) TFR(24)
  x0 += k1; x1 += k2 + 4u;
  TFR(13) TFR(15) TFR(26) TFR(6)
  x0 += k2; x1 += k0 + 5u;
#undef TFR
  return {x0, x1};
}

__device__ __forceinline__ float u01f(uint32_t bits) {
  // JAX uniform: bitcast((bits>>9)|0x3f800000) - 1.0  in [0,1)
  return __uint_as_float((bits >> 9) | 0x3f800000u) - 1.0f;
}

#if TF_PARTITIONABLE
// partitionable: per-element 64-bit counter (hi=0 for our sizes), bits = o1^o2
__device__ __forceinline__ uint32_t rbits(uint32_t ka, uint32_t kb, uint32_t idx, uint32_t /*size*/) {
  U2 r = tf2x32(ka, kb, 0u, idx);
  return r.x ^ r.y;
}
#else
// original: counts = iota(size) split in halves, (x0,x1)=(i, i+half)
__device__ __forceinline__ uint32_t rbits(uint32_t ka, uint32_t kb, uint32_t idx, uint32_t size) {
  uint32_t half = size >> 1;
  if (idx < half) { U2 r = tf2x32(ka, kb, idx, idx + half); return r.x; }
  U2 r = tf2x32(ka, kb, idx - half, idx); return r.y;
}
#endif

__device__ __forceinline__ void split_keys(uint32_t& k1a, uint32_t& k1b, uint32_t& k2a, uint32_t& k2b) {
  // key(1234) = (0, 1234)
#if TF_PARTITIONABLE
  U2 t0 = tf2x32(0u, 1234u, 0u, 0u); k1a = t0.x; k1b = t0.y;
  U2 t1 = tf2x32(0u, 1234u, 0u, 1u); k2a = t1.x; k2b = t1.y;
#else
  U2 t0 = tf2x32(0u, 1234u, 0u, 2u);   // lane0 of counts [0,1,2,3]
  U2 t1 = tf2x32(0u, 1234u, 1u, 3u);   // lane1
  k1a = t0.x; k1b = t1.x; k2a = t0.y; k2b = t1.y;
#endif
}

// ---------------- K1/K4: tiled fp32 GEMM  C = X @ W^T + bias ----------------
// MODE 0: QKV projection. M=25216 (= L*N), Nout=2304; input pointer depends on
//         j-range (q/k/v); output scattered to per-(b,l,d) head layout; q scaled 1/8.
// MODE 1: out-projection. M=32896 (= Lt*N), Nout=768; plain row-major output.
// BM=128, BN=64, BK=16, 256 threads, 8x4 micro-tile. K=768 exact (48 iters).
template <int MODE>
__global__ __launch_bounds__(256) void gemm_kernel(
    const float* __restrict__ X0, const float* __restrict__ X1, const float* __restrict__ X2,
    const float* __restrict__ W, const float* __restrict__ bias,
    float* __restrict__ O0, float* __restrict__ O1, float* __restrict__ O2)
{
  __shared__ float As[16][132];  // k-major, padded (132%4==0 keeps float4 align)
  __shared__ float Bs[16][68];
  const int bm = blockIdx.x, bn = blockIdx.y;
  const int tid = threadIdx.x;
  const int tx = tid & 15, ty = tid >> 4;
  const int wrow0 = bn * 64;

  const float* X;
  if (MODE == 0) {
    const int which = bn / 12;   // BN=64 aligns with heads: 12 head-tiles per matrix
    X = which == 0 ? X0 : (which == 1 ? X1 : X2);
  } else {
    X = X0;
  }

  float acc[8][4];
#pragma unroll
  for (int i = 0; i < 8; i++)
#pragma unroll
    for (int j = 0; j < 4; j++) acc[i][j] = 0.0f;

  for (int kt = 0; kt < 48; kt++) {
#pragma unroll
    for (int li = 0; li < 2; li++) {
      int idx = tid + li * 256;
      int r = idx >> 2, c4 = idx & 3;
      float4 a = *(const float4*)(X + (size_t)(bm * 128 + r) * 768 + kt * 16 + c4 * 4);
      As[c4 * 4 + 0][r] = a.x;
      As[c4 * 4 + 1][r] = a.y;
      As[c4 * 4 + 2][r] = a.z;
      As[c4 * 4 + 3][r] = a.w;
    }
    {
      int c = tid >> 2, c4 = tid & 3;
      float4 bv = *(const float4*)(W + (size_t)(wrow0 + c) * 768 + kt * 16 + c4 * 4);
      Bs[c4 * 4 + 0][c] = bv.x;
      Bs[c4 * 4 + 1][c] = bv.y;
      Bs[c4 * 4 + 2][c] = bv.z;
      Bs[c4 * 4 + 3][c] = bv.w;
    }
    __syncthreads();
#pragma unroll
    for (int kk = 0; kk < 16; kk++) {
      float4 a0 = *(const float4*)&As[kk][ty * 8];
      float4 a1 = *(const float4*)&As[kk][ty * 8 + 4];
      float4 b0 = *(const float4*)&Bs[kk][tx * 4];
      float av[8] = {a0.x, a0.y, a0.z, a0.w, a1.x, a1.y, a1.z, a1.w};
      float bv[4] = {b0.x, b0.y, b0.z, b0.w};
#pragma unroll
      for (int i = 0; i < 8; i++)
#pragma unroll
        for (int j = 0; j < 4; j++) acc[i][j] = fmaf(av[i], bv[j], acc[i][j]);
    }
    __syncthreads();
  }

  float4 bb = *(const float4*)(bias + wrow0 + tx * 4);
  if (MODE == 0) {
    const int which = bn / 12, h = bn % 12;
    float* O = which == 0 ? O0 : (which == 1 ? O1 : O2);
    const float scale = (which == 0) ? 0.125f : 1.0f;  // q = (xW+b)/sqrt(64)
#pragma unroll
    for (int i = 0; i < 8; i++) {
      int m = bm * 128 + ty * 8 + i;       // m = l*128 + n  ((L,N,E) row-major)
      int l = m >> 7, n = m & 127;
      float4 o;
      o.x = (acc[i][0] + bb.x) * scale;
      o.y = (acc[i][1] + bb.y) * scale;
      o.z = (acc[i][2] + bb.z) * scale;
      o.w = (acc[i][3] + bb.w) * scale;
      *(float4*)(O + ((size_t)((n * 12 + h) * 197 + l)) * 64 + tx * 4) = o;
    }
  } else {
#pragma unroll
    for (int i = 0; i < 8; i++) {
      int m = bm * 128 + ty * 8 + i;
      float4 o;
      o.x = acc[i][0] + bb.x;
      o.y = acc[i][1] + bb.y;
      o.z = acc[i][2] + bb.z;
      o.w = acc[i][3] + bb.w;
      *(float4*)(O0 + (size_t)m * 768 + wrow0 + tx * 4) = o;
    }
  }
}

// ---------------- K2: center row (= S[b,0,:]) and its norm ----------------
__global__ __launch_bounds__(256) void center_kernel(
    const float* __restrict__ q_ws, const float* __restrict__ k_ws,
    float* __restrict__ center, float* __restrict__ cnorm)
{
  const int b = blockIdx.x;
  const int lane = threadIdx.x & 63, w = threadIdx.x >> 6;
  __shared__ float ssh[4];
  const float q0 = q_ws[(size_t)b * (197 * 64) + lane];   // row 0, d = lane
  float ss = 0.0f;
  for (int s = w; s < 197; s += 4) {
    float val = q0 * k_ws[((size_t)b * 197 + s) * 64 + lane];
#pragma unroll
    for (int off = 32; off >= 1; off >>= 1) val += __shfl_xor(val, off, 64);
    if (lane == 0) center[(size_t)b * 197 + s] = val;
    ss += val * val;
  }
  if (lane == 0) ssh[w] = ss;
  __syncthreads();
  if (threadIdx.x == 0) cnorm[b] = sqrtf(ssh[0] + ssh[1] + ssh[2] + ssh[3]);
}

// ---------------- K3 helpers ----------------
__device__ __forceinline__ void softmax_row(float x0, float x1, float x2, float x3,
                                            bool v3, float* p)
{
  float m = fmaxf(fmaxf(x0, x1), x2);
  if (v3) m = fmaxf(m, x3);
#pragma unroll
  for (int off = 32; off >= 1; off >>= 1) m = fmaxf(m, __shfl_xor(m, off, 64));
  float e0 = __expf(x0 - m), e1 = __expf(x1 - m), e2 = __expf(x2 - m);
  float e3 = v3 ? __expf(x3 - m) : 0.0f;
  float s = e0 + e1 + e2 + e3;
#pragma unroll
  for (int off = 32; off >= 1; off >>= 1) s += __shfl_xor(s, off, 64);
  float rs = 1.0f / s;
  p[0] = e0 * rs; p[1] = e1 * rs; p[2] = e2 * rs; p[3] = e3 * rs;
}

__device__ __forceinline__ void weights_add(float* __restrict__ awn, int t, int lane,
                                            bool v3, const float* p)
{
  float* a = awn + (size_t)t * 197;
  const float c = 1.0f / 12.0f;
  atomicAdd(a + lane, p[0] * c);
  atomicAdd(a + lane + 64, p[1] * c);
  atomicAdd(a + lane + 128, p[2] * c);
  if (v3) atomicAdd(a + lane + 192, p[3] * c);
}

// PV: o[d=lane] = sum_s p[s] * v[s][d]; p lives in registers (lane <-> s=lane+64j),
// broadcast via __shfl. v streamed from global (L2-resident per b).
template <int NR>
__device__ __forceinline__ void pv_store(const float* __restrict__ vg, float p[NR][4],
                                         int t0, int n, int h, int lane,
                                         float* __restrict__ out_pre)
{
  float o[NR];
#pragma unroll
  for (int i = 0; i < NR; i++) o[i] = 0.0f;
#pragma unroll
  for (int j = 0; j < 4; j++) {
    const int send = (j < 3) ? 64 : 5;   // 197 = 3*64 + 5
    for (int si = 0; si < send; si++) {
      const int s = j * 64 + si;
      float vv = vg[(size_t)s * 64 + lane];
#pragma unroll
      for (int i = 0; i < NR; i++) {
        float ps = __shfl(p[i][j], si, 64);
        o[i] = fmaf(ps, vv, o[i]);
      }
    }
  }
#pragma unroll
  for (int i = 0; i < NR; i++)
    out_pre[((size_t)(t0 + i) * 128 + n) * 768 + h * 64 + lane] = o[i];
}

// ---------------- K3: fused scores + RNG rows + softmax + PV + weights ----------------
// One block per b (=n*12+h), 512 threads (8 waves). LDS ~61KB -> 2 blocks/CU.
// Rows 0..60 (center + random) processed one row per wave; rows 61..256 in
// per-wave 4-row batches with a register-tiled q@kT matvec.
__global__ __launch_bounds__(512) void attn_kernel(
    const float* __restrict__ q_ws, const float* __restrict__ k_ws, const float* __restrict__ v_ws,
    const float* __restrict__ center, const float* __restrict__ cnorm,
    float* __restrict__ out_pre, float* __restrict__ attn_w)
{
  __shared__ float kT[64][200];     // kT[d][s]: lanes read consecutive s -> conflict-free
  __shared__ float qbw[8][4][64];   // per-wave staged q rows
  __shared__ float cen[200];
  __shared__ float uu[200];

  const int b = blockIdx.x;
  const int n = b / 12, h = b % 12;
  const int tid = threadIdx.x;
  const int lane = tid & 63, w = tid >> 6;
  const bool v3 = lane < 5;         // slot j=3 valid only for s=192..196

  const float* kg = k_ws + (size_t)b * (197 * 64);
  const float* vg = v_ws + (size_t)b * (197 * 64);
  const float* qg = q_ws + (size_t)b * (197 * 64);

  for (int idx = tid; idx < 197 * 64; idx += 512)
    kT[idx & 63][idx >> 6] = kg[idx];
  {
    float inv = 1.0f / fmaxf(cnorm[b], EPSc);
    for (int s = tid; s < 197; s += 512) {
      float c = center[(size_t)b * 197 + s];
      cen[s] = c;
      uu[s] = c * inv;
    }
  }
  __syncthreads();

  const float cnb = cnorm[b];
  uint32_t k1a, k1b, k2a, k2b;
  split_keys(k1a, k1b, k2a, k2b);
  float* awn = attn_w + (size_t)n * (LTc * 197);

  // ---- rows 0..60: center copy (t=0) + random rows (t=1..60) ----
  for (int t = w; t <= 60; t += 8) {
    float x0, x1, x2, x3;
    if (t == 0) {
      x0 = cen[lane]; x1 = cen[lane + 64]; x2 = cen[lane + 128];
      x3 = v3 ? cen[lane + 192] : 0.0f;
    } else {
      const int ns = t - 1;
      const uint32_t base = ((uint32_t)ns * 1536u + (uint32_t)b) * 197u;
      float r0 = u01f(rbits(k1a, k1b, base + lane,        RSZc)) * 2.0f - 1.0f;
      float r1 = u01f(rbits(k1a, k1b, base + lane + 64,   RSZc)) * 2.0f - 1.0f;
      float r2 = u01f(rbits(k1a, k1b, base + lane + 128,  RSZc)) * 2.0f - 1.0f;
      float r3 = v3 ? (u01f(rbits(k1a, k1b, base + lane + 192, RSZc)) * 2.0f - 1.0f) : 0.0f;
      float us0 = uu[lane], us1 = uu[lane + 64], us2 = uu[lane + 128];
      float us3 = v3 ? uu[lane + 192] : 0.0f;
      float pa = r0 * us0 + r1 * us1 + r2 * us2 + r3 * us3;
#pragma unroll
      for (int off = 32; off >= 1; off >>= 1) pa += __shfl_xor(pa, off, 64);
      float rp0 = r0 - pa * us0, rp1 = r1 - pa * us1;
      float rp2 = r2 - pa * us2, rp3 = r3 - pa * us3;
      float sq2 = rp0 * rp0 + rp1 * rp1 + rp2 * rp2 + (v3 ? rp3 * rp3 : 0.0f);
#pragma unroll
      for (int off = 32; off >= 1; off >>= 1) sq2 += __shfl_xor(sq2, off, 64);
      float invn = 1.0f / fmaxf(sqrtf(sq2), EPSc);
      float cv = u01f(rbits(k2a, k2b, (uint32_t)ns, 60u)) * 0.2f + 0.7f;
      float sv = sqrtf(1.0f - cv * cv);
      float f = sv * invn;
      x0 = cnb * (cv * us0 + f * rp0);
      x1 = cnb * (cv * us1 + f * rp1);
      x2 = cnb * (cv * us2 + f * rp2);
      x3 = cnb * (cv * us3 + f * rp3);
    }
    float pr[1][4];
    softmax_row(x0, x1, x2, x3, v3, pr[0]);
    weights_add(awn, t, lane, v3, pr[0]);
    pv_store<1>(vg, pr, t, n, h, lane, out_pre);
  }

  // ---- rows 61..256: 49 four-row batches, register-tiled q @ kT ----
  for (int bi = w; bi < 49; bi += 8) {
    const int t0 = 61 + bi * 4;
    const int l0 = t0 - 60;
#pragma unroll
    for (int i = 0; i < 4; i++)
      qbw[w][i][lane] = qg[(size_t)(l0 + i) * 64 + lane];  // wave-private, in-order LDS

    float acc[4][4] = {};
#pragma unroll 4
    for (int d = 0; d < 64; d++) {
      float q0 = qbw[w][0][d], q1 = qbw[w][1][d], q2 = qbw[w][2][d], q3 = qbw[w][3][d];
      float kv0 = kT[d][lane], kv1 = kT[d][lane + 64], kv2 = kT[d][lane + 128];
      float kv3 = v3 ? kT[d][lane + 192] : 0.0f;
      acc[0][0] = fmaf(q0, kv0, acc[0][0]); acc[0][1] = fmaf(q0, kv1, acc[0][1]);
      acc[0][2] = fmaf(q0, kv2, acc[0][2]); acc[0][3] = fmaf(q0, kv3, acc[0][3]);
      acc[1][0] = fmaf(q1, kv0, acc[1][0]); acc[1][1] = fmaf(q1, kv1, acc[1][1]);
      acc[1][2] = fmaf(q1, kv2, acc[1][2]); acc[1][3] = fmaf(q1, kv3, acc[1][3]);
      acc[2][0] = fmaf(q2, kv0, acc[2][0]); acc[2][1] = fmaf(q2, kv1, acc[2][1]);
      acc[2][2] = fmaf(q2, kv2, acc[2][2]); acc[2][3] = fmaf(q2, kv3, acc[2][3]);
      acc[3][0] = fmaf(q3, kv0, acc[3][0]); acc[3][1] = fmaf(q3, kv1, acc[3][1]);
      acc[3][2] = fmaf(q3, kv2, acc[3][2]); acc[3][3] = fmaf(q3, kv3, acc[3][3]);
    }
    float pr[4][4];
#pragma unroll
    for (int i = 0; i < 4; i++) {
      softmax_row(acc[i][0], acc[i][1], acc[i][2], acc[i][3], v3, pr[i]);
      weights_add(awn, t0 + i, lane, v3, pr[i]);
    }
    pv_store<4>(vg, pr, t0, n, h, lane, out_pre);
  }
}

// ---------------- launch ----------------
extern "C" void kernel_launch(void* const* d_in, const int* in_sizes, int n_in,
                              void* d_out, int out_size, void* d_ws, size_t ws_size,
                              hipStream_t stream)
{
  const float* query = (const float*)d_in[0];
  const float* key   = (const float*)d_in[1];
  const float* value = (const float*)d_in[2];
  const float* w_in  = (const float*)d_in[3];
  const float* b_in  = (const float*)d_in[4];
  const float* w_out = (const float*)d_in[5];
  const float* b_out = (const float*)d_in[6];

  float* out    = (float*)d_out;                       // (257,128,768)
  float* attn_w = out + (size_t)LTc * Nc * Ec;         // (128,257,197)

  // workspace layout (fp32): q,k,v per-head [B][L][64]; center [B][L]; cnorm;
  // out_pre [Lt*N][768]. Total ~335 MB.
  float* ws      = (float*)d_ws;
  float* q_ws    = ws;
  float* k_ws    = q_ws + (size_t)Bc * Lc * HDc;
  float* v_ws    = k_ws + (size_t)Bc * Lc * HDc;
  float* center  = v_ws + (size_t)Bc * Lc * HDc;
  float* cnorm   = center + (size_t)Bc * Lc;
  float* out_pre = cnorm + 2048;                       // padded for alignment

  (void)in_sizes; (void)n_in; (void)out_size; (void)ws_size;

  // attn_weights accumulated atomically -> zero it (d_out is poisoned 0xAA)
  hipMemsetAsync(attn_w, 0, (size_t)Nc * LTc * Lc * sizeof(float), stream);

  gemm_kernel<0><<<dim3(197, 36), 256, 0, stream>>>(query, key, value, w_in, b_in,
                                                    q_ws, k_ws, v_ws);
  center_kernel<<<dim3(1536), 256, 0, stream>>>(q_ws, k_ws, center, cnorm);
  attn_kernel<<<dim3(1536), 512, 0, stream>>>(q_ws, k_ws, v_ws, center, cnorm,
                                              out_pre, attn_w);
  gemm_kernel<1><<<dim3(257, 12), 256, 0, stream>>>(out_pre, nullptr, nullptr,
                                                    w_out, b_out, out, nullptr, nullptr);
}

// Round 2
// 1890.255 us; speedup vs baseline: 1.5840x; 1.5840x over previous
//
#include <hip/hip_runtime.h>
#include <stdint.h>

// ---------------- problem constants ----------------
constexpr int Lc  = 197;
constexpr int Nc  = 128;
constexpr int Ec  = 768;
constexpr int HDc = 64;
constexpr int Bc  = Nc * 12;        // 1536 batch*heads
constexpr int LTc = Lc + 60;        // 257 output rows
constexpr float EPSc = 1e-12f;

// ---------------- threefry2x32 (JAX-exact, partitionable variant) ----------------
struct U2 { uint32_t x, y; };

__device__ __forceinline__ U2 tf2x32(uint32_t k0, uint32_t k1, uint32_t x0, uint32_t x1) {
  uint32_t k2 = k0 ^ k1 ^ 0x1BD11BDAu;
  x0 += k0; x1 += k1;
#define TFR(r) { x0 += x1; x1 = (x1 << (r)) | (x1 >> (32 - (r))); x1 ^= x0; }
  TFR(13) TFR(15) TFR(26) TFR(6)
  x0 += k1; x1 += k2 + 1u;
  TFR(17) TFR(29) TFR(16) TFR(24)
  x0 += k2; x1 += k0 + 2u;
  TFR(13) TFR(15) TFR(26) TFR(6)
  x0 += k0; x1 += k1 + 3u;
  TFR(17) TFR(29) TFR(16) TFR(24)
  x0 += k1; x1 += k2 + 4u;
  TFR(13) TFR(15) TFR(26) TFR(6)
  x0 += k2; x1 += k0 + 5u;
#undef TFR
  return {x0, x1};
}

__device__ __forceinline__ float u01f(uint32_t bits) {
  return __uint_as_float((bits >> 9) | 0x3f800000u) - 1.0f;
}

__device__ __forceinline__ uint32_t rbits(uint32_t ka, uint32_t kb, uint32_t idx) {
  U2 r = tf2x32(ka, kb, 0u, idx);
  return r.x ^ r.y;
}

__device__ __forceinline__ void split_keys(uint32_t& k1a, uint32_t& k1b, uint32_t& k2a, uint32_t& k2b) {
  U2 t0 = tf2x32(0u, 1234u, 0u, 0u); k1a = t0.x; k1b = t0.y;
  U2 t1 = tf2x32(0u, 1234u, 0u, 1u); k2a = t1.x; k2b = t1.y;
}

// ---------------- fp32 -> bf16 hi/lo split (trunc hi + exact residual) ----------------
// hi = chop(f) (<=1ulp_bf16 err toward 0), lo = chop(f - hi_f). Combined rel err ~2^-16.
__device__ __forceinline__ void f2hilo(float f, unsigned short& h, unsigned short& l) {
  uint32_t u = __float_as_uint(f);
  h = (unsigned short)(u >> 16);
  float lof = f - __uint_as_float(u & 0xffff0000u);
  l = (unsigned short)(__float_as_uint(lof) >> 16);
}

// src: rows x 768 fp32, dst: rows x 1536 bf16 (cols 0..767 = hi, 768..1535 = lo)
__global__ __launch_bounds__(256) void convert_hilo(const float* __restrict__ src,
                                                    unsigned short* __restrict__ dst,
                                                    int rows)
{
  int idx = blockIdx.x * 256 + threadIdx.x;   // one float4 per thread
  int total = rows * 192;
  if (idx >= total) return;
  int m = idx / 192, c = (idx % 192) * 4;
  float4 f = *(const float4*)(src + (size_t)m * 768 + c);
  ushort4 hv, lv;
  f2hilo(f.x, hv.x, lv.x);
  f2hilo(f.y, hv.y, lv.y);
  f2hilo(f.z, hv.z, lv.z);
  f2hilo(f.w, hv.w, lv.w);
  *(ushort4*)(dst + (size_t)m * 1536 + c) = hv;
  *(ushort4*)(dst + (size_t)m * 1536 + 768 + c) = lv;
}

// ---------------- MFMA bf16 GEMM: C = A(bf16 hi|lo, MxK=1536) @ Wb^T + bias ----------------
// MODE 0: QKV proj. M=25216 (l*128+n). Output scattered to per-head fp32 q/k/v, q scaled 1/8.
//         Column-tile index bn in 0..17; which = bn/6 selects q/k/v input & output.
// MODE 1: out-proj. M=32896 (t*128+n), Nout=768 row-major + bias.
// 256 thr = 4 waves (2x2 of 64x64), BM=BN=128, BK=32, 16x16x32 bf16 MFMA.
typedef __attribute__((ext_vector_type(8))) short bfrag_t;
typedef __attribute__((ext_vector_type(4))) float accfrag_t;

template <int MODE>
__global__ __launch_bounds__(256) void gemm_mfma(
    const unsigned short* __restrict__ A0, const unsigned short* __restrict__ A1,
    const unsigned short* __restrict__ A2in, const unsigned short* __restrict__ Wb,
    const float* __restrict__ bias, int cb,
    float* __restrict__ O0, float* __restrict__ O1, float* __restrict__ O2)
{
  __shared__ unsigned short As[128 * 40];   // stride 40 bf16 = 80 B -> 2-way max on b128 frag reads
  __shared__ unsigned short Bs[128 * 40];
  const int bm = blockIdx.x;
  const int bn = cb + blockIdx.y;
  const int tid = threadIdx.x;
  const int lane = tid & 63, wv = tid >> 6;
  const int wm = (wv & 1) * 64, wn = (wv >> 1) * 64;
  const int q4 = lane >> 4, l16 = lane & 15;

  const unsigned short* A;
  int which = 0;
  if (MODE == 0) { which = bn / 6; A = which == 0 ? A0 : (which == 1 ? A1 : A2in); }
  else A = A0;

  const int sr = tid >> 2;           // staging row within 64-row half
  const int sc = (tid & 3) * 8;      // staging col (8 bf16 = 16 B)

  accfrag_t acc[4][4];
#pragma unroll
  for (int i = 0; i < 4; i++)
#pragma unroll
    for (int j = 0; j < 4; j++)
#pragma unroll
      for (int r = 0; r < 4; r++) acc[i][j][r] = 0.0f;

  for (int kt = 0; kt < 48; kt++) {
    const int k0 = kt * 32;
    __syncthreads();
#pragma unroll
    for (int p = 0; p < 2; p++) {
      int r = p * 64 + sr;
      uint4 av = *(const uint4*)(A  + (size_t)(bm * 128 + r) * 1536 + k0 + sc);
      *(uint4*)&As[r * 40 + sc] = av;
      uint4 bv = *(const uint4*)(Wb + (size_t)(bn * 128 + r) * 1536 + k0 + sc);
      *(uint4*)&Bs[r * 40 + sc] = bv;
    }
    __syncthreads();
    bfrag_t af[4], bf[4];
#pragma unroll
    for (int i = 0; i < 4; i++) {
      af[i] = *(const bfrag_t*)&As[(wm + i * 16 + l16) * 40 + q4 * 8];
      bf[i] = *(const bfrag_t*)&Bs[(wn + i * 16 + l16) * 40 + q4 * 8];
    }
#pragma unroll
    for (int i = 0; i < 4; i++)
#pragma unroll
      for (int j = 0; j < 4; j++)
        acc[i][j] = __builtin_amdgcn_mfma_f32_16x16x32_bf16(af[i], bf[j], acc[i][j], 0, 0, 0);
  }

  float bv4[4];
#pragma unroll
  for (int j = 0; j < 4; j++) bv4[j] = bias[bn * 128 + wn + j * 16 + l16];

  if (MODE == 0) {
    const float scale = (which == 0) ? 0.125f : 1.0f;
    float* O = which == 0 ? O0 : (which == 1 ? O1 : O2);
#pragma unroll
    for (int i = 0; i < 4; i++) {
#pragma unroll
      for (int r = 0; r < 4; r++) {
        int m = bm * 128 + wm + i * 16 + q4 * 4 + r;   // m = l*128 + n
        int l = m >> 7, nb = m & 127;
#pragma unroll
        for (int j = 0; j < 4; j++) {
          int ng = bn * 128 + wn + j * 16 + l16;
          int nc = ng - which * 768;
          int h = nc >> 6, d = nc & 63;
          O[(((size_t)(nb * 12 + h)) * 197 + l) * 64 + d] = (acc[i][j][r] + bv4[j]) * scale;
        }
      }
    }
  } else {
#pragma unroll
    for (int i = 0; i < 4; i++) {
#pragma unroll
      for (int r = 0; r < 4; r++) {
        int m = bm * 128 + wm + i * 16 + q4 * 4 + r;
#pragma unroll
        for (int j = 0; j < 4; j++) {
          int ng = bn * 128 + wn + j * 16 + l16;
          O0[(size_t)m * 768 + ng] = acc[i][j][r] + bv4[j];
        }
      }
    }
  }
}

// ---------------- K2: center row (= S[b,0,:]) and its norm ----------------
__global__ __launch_bounds__(256) void center_kernel(
    const float* __restrict__ q_ws, const float* __restrict__ k_ws,
    float* __restrict__ center, float* __restrict__ cnorm)
{
  const int b = blockIdx.x;
  const int lane = threadIdx.x & 63, w = threadIdx.x >> 6;
  __shared__ float ssh[4];
  const float q0 = q_ws[(size_t)b * (197 * 64) + lane];
  float ss = 0.0f;
  for (int s = w; s < 197; s += 4) {
    float val = q0 * k_ws[((size_t)b * 197 + s) * 64 + lane];
#pragma unroll
    for (int off = 32; off >= 1; off >>= 1) val += __shfl_xor(val, off, 64);
    if (lane == 0) center[(size_t)b * 197 + s] = val;
    ss += val * val;
  }
  if (lane == 0) ssh[w] = ss;
  __syncthreads();
  if (threadIdx.x == 0) cnorm[b] = sqrtf(ssh[0] + ssh[1] + ssh[2] + ssh[3]);
}

// ---------------- K3 helpers ----------------
__device__ __forceinline__ void softmax_row(float x0, float x1, float x2, float x3,
                                            bool v3, float* p)
{
  float m = fmaxf(fmaxf(x0, x1), x2);
  if (v3) m = fmaxf(m, x3);
#pragma unroll
  for (int off = 32; off >= 1; off >>= 1) m = fmaxf(m, __shfl_xor(m, off, 64));
  float e0 = __expf(x0 - m), e1 = __expf(x1 - m), e2 = __expf(x2 - m);
  float e3 = v3 ? __expf(x3 - m) : 0.0f;
  float s = e0 + e1 + e2 + e3;
#pragma unroll
  for (int off = 32; off >= 1; off >>= 1) s += __shfl_xor(s, off, 64);
  float rs = 1.0f / s;
  p[0] = e0 * rs; p[1] = e1 * rs; p[2] = e2 * rs; p[3] = e3 * rs;
}

__device__ __forceinline__ void weights_add(float* __restrict__ awn, int t, int lane,
                                            bool v3, const float* p)
{
  float* a = awn + (size_t)t * 197;
  const float c = 1.0f / 12.0f;
  atomicAdd(a + lane, p[0] * c);
  atomicAdd(a + lane + 64, p[1] * c);
  atomicAdd(a + lane + 128, p[2] * c);
  if (v3) atomicAdd(a + lane + 192, p[3] * c);
}

// PV for 4 rows: o[d=lane] = sum_s p[s] * v[s][d]; 4 independent fma chains.
// Output written as bf16 hi/lo into the GEMM2 A-buffer (row m = t*128+n, col h*64+d | +768).
__device__ __forceinline__ void pv_store4(const float* __restrict__ vg, float p[4][4],
                                          int t0, int nval, int n, int h, int lane,
                                          unsigned short* __restrict__ A2)
{
  float o[4] = {0.0f, 0.0f, 0.0f, 0.0f};
#pragma unroll
  for (int j = 0; j < 4; j++) {
    const int send = (j < 3) ? 64 : 5;   // 197 = 3*64 + 5
    for (int si = 0; si < send; si++) {
      const int s = j * 64 + si;
      float vv = vg[(size_t)s * 64 + lane];
#pragma unroll
      for (int i = 0; i < 4; i++) {
        float ps = __shfl(p[i][j], si, 64);
        o[i] = fmaf(ps, vv, o[i]);
      }
    }
  }
#pragma unroll
  for (int i = 0; i < 4; i++) {
    if (i < nval) {
      unsigned short hb, lb;
      f2hilo(o[i], hb, lb);
      size_t base = ((size_t)(t0 + i) * 128 + n) * 1536 + h * 64 + lane;
      A2[base] = hb;
      A2[base + 768] = lb;
    }
  }
}

// ---------------- K3: fused scores + RNG rows + softmax + PV + weights ----------------
__global__ __launch_bounds__(512) void attn_kernel(
    const float* __restrict__ q_ws, const float* __restrict__ k_ws, const float* __restrict__ v_ws,
    const float* __restrict__ center, const float* __restrict__ cnorm,
    unsigned short* __restrict__ A2, float* __restrict__ attn_w)
{
  __shared__ float kT[64][201];     // 201: staging banks (9d+s)%32 -> 2-way max; frag reads conflict-free
  __shared__ float qbw[8][4][64];
  __shared__ float cen[200];
  __shared__ float uu[200];

  const int b = blockIdx.x;
  const int n = b / 12, h = b % 12;
  const int tid = threadIdx.x;
  const int lane = tid & 63, w = tid >> 6;
  const bool v3 = lane < 5;

  const float* kg = k_ws + (size_t)b * (197 * 64);
  const float* vg = v_ws + (size_t)b * (197 * 64);
  const float* qg = q_ws + (size_t)b * (197 * 64);

  for (int idx = tid; idx < 197 * 64; idx += 512)
    kT[idx & 63][idx >> 6] = kg[idx];
  {
    float inv = 1.0f / fmaxf(cnorm[b], EPSc);
    for (int s = tid; s < 197; s += 512) {
      float c = center[(size_t)b * 197 + s];
      cen[s] = c;
      uu[s] = c * inv;
    }
  }
  __syncthreads();

  const float cnb = cnorm[b];
  uint32_t k1a, k1b, k2a, k2b;
  split_keys(k1a, k1b, k2a, k2b);
  float* awn = attn_w + (size_t)n * (LTc * 197);

  // ---- rows 0..60 in 16 groups of 4 (group 15: only t=60 valid) ----
  for (int g = w; g < 16; g += 8) {
    const int t0 = g * 4;
    const int nval = (g == 15) ? 1 : 4;
    float pr[4][4];
#pragma unroll
    for (int i = 0; i < 4; i++) {
      if (i >= nval) { pr[i][0] = pr[i][1] = pr[i][2] = pr[i][3] = 0.0f; continue; }
      const int t = t0 + i;
      float x0, x1, x2, x3;
      if (t == 0) {
        x0 = cen[lane]; x1 = cen[lane + 64]; x2 = cen[lane + 128];
        x3 = v3 ? cen[lane + 192] : 0.0f;
      } else {
        const int ns = t - 1;
        const uint32_t base = ((uint32_t)ns * 1536u + (uint32_t)b) * 197u;
        float r0 = u01f(rbits(k1a, k1b, base + lane))       * 2.0f - 1.0f;
        float r1 = u01f(rbits(k1a, k1b, base + lane + 64))  * 2.0f - 1.0f;
        float r2 = u01f(rbits(k1a, k1b, base + lane + 128)) * 2.0f - 1.0f;
        float r3 = v3 ? (u01f(rbits(k1a, k1b, base + lane + 192)) * 2.0f - 1.0f) : 0.0f;
        float us0 = uu[lane], us1 = uu[lane + 64], us2 = uu[lane + 128];
        float us3 = v3 ? uu[lane + 192] : 0.0f;
        float pa = r0 * us0 + r1 * us1 + r2 * us2 + r3 * us3;
#pragma unroll
        for (int off = 32; off >= 1; off >>= 1) pa += __shfl_xor(pa, off, 64);
        float rp0 = r0 - pa * us0, rp1 = r1 - pa * us1;
        float rp2 = r2 - pa * us2, rp3 = r3 - pa * us3;
        float sq2 = rp0 * rp0 + rp1 * rp1 + rp2 * rp2 + (v3 ? rp3 * rp3 : 0.0f);
#pragma unroll
        for (int off = 32; off >= 1; off >>= 1) sq2 += __shfl_xor(sq2, off, 64);
        float invn = 1.0f / fmaxf(sqrtf(sq2), EPSc);
        float cv = u01f(rbits(k2a, k2b, (uint32_t)ns)) * 0.2f + 0.7f;
        float sv = sqrtf(1.0f - cv * cv);
        float f = sv * invn;
        x0 = cnb * (cv * us0 + f * rp0);
        x1 = cnb * (cv * us1 + f * rp1);
        x2 = cnb * (cv * us2 + f * rp2);
        x3 = cnb * (cv * us3 + f * rp3);
      }
      softmax_row(x0, x1, x2, x3, v3, pr[i]);
      weights_add(awn, t, lane, v3, pr[i]);
    }
    pv_store4(vg, pr, t0, nval, n, h, lane, A2);
  }

  // ---- rows 61..256: 49 four-row batches, register-tiled q @ kT ----
  for (int bi = w; bi < 49; bi += 8) {
    const int t0 = 61 + bi * 4;
    const int l0 = t0 - 60;
#pragma unroll
    for (int i = 0; i < 4; i++)
      qbw[w][i][lane] = qg[(size_t)(l0 + i) * 64 + lane];

    float acc[4][4] = {};
#pragma unroll 4
    for (int d = 0; d < 64; d++) {
      float q0 = qbw[w][0][d], q1 = qbw[w][1][d], q2 = qbw[w][2][d], q3 = qbw[w][3][d];
      float kv0 = kT[d][lane], kv1 = kT[d][lane + 64], kv2 = kT[d][lane + 128];
      float kv3 = v3 ? kT[d][lane + 192] : 0.0f;
      acc[0][0] = fmaf(q0, kv0, acc[0][0]); acc[0][1] = fmaf(q0, kv1, acc[0][1]);
      acc[0][2] = fmaf(q0, kv2, acc[0][2]); acc[0][3] = fmaf(q0, kv3, acc[0][3]);
      acc[1][0] = fmaf(q1, kv0, acc[1][0]); acc[1][1] = fmaf(q1, kv1, acc[1][1]);
      acc[1][2] = fmaf(q1, kv2, acc[1][2]); acc[1][3] = fmaf(q1, kv3, acc[1][3]);
      acc[2][0] = fmaf(q2, kv0, acc[2][0]); acc[2][1] = fmaf(q2, kv1, acc[2][1]);
      acc[2][2] = fmaf(q2, kv2, acc[2][2]); acc[2][3] = fmaf(q2, kv3, acc[2][3]);
      acc[3][0] = fmaf(q3, kv0, acc[3][0]); acc[3][1] = fmaf(q3, kv1, acc[3][1]);
      acc[3][2] = fmaf(q3, kv2, acc[3][2]); acc[3][3] = fmaf(q3, kv3, acc[3][3]);
    }
    float pr[4][4];
#pragma unroll
    for (int i = 0; i < 4; i++) {
      softmax_row(acc[i][0], acc[i][1], acc[i][2], acc[i][3], v3, pr[i]);
      weights_add(awn, t0 + i, lane, v3, pr[i]);
    }
    pv_store4(vg, pr, t0, 4, n, h, lane, A2);
  }
}

// ---------------- launch ----------------
extern "C" void kernel_launch(void* const* d_in, const int* in_sizes, int n_in,
                              void* d_out, int out_size, void* d_ws, size_t ws_size,
                              hipStream_t stream)
{
  const float* query = (const float*)d_in[0];
  const float* key   = (const float*)d_in[1];
  const float* value = (const float*)d_in[2];
  const float* w_in  = (const float*)d_in[3];
  const float* b_in  = (const float*)d_in[4];
  const float* w_out = (const float*)d_in[5];
  const float* b_out = (const float*)d_in[6];

  float* out    = (float*)d_out;                       // (257,128,768)
  float* attn_w = out + (size_t)LTc * Nc * Ec;         // (128,257,197)

  // ---- workspace layout (bytes) ----
  constexpr size_t SZ_HEADF = (size_t)Bc * Lc * HDc * 4;   // 77,463,552 per fp32 head buf
  constexpr size_t OFF_CEN  = 3 * SZ_HEADF;
  constexpr size_t OFF_CN   = OFF_CEN + (size_t)Bc * Lc * 4;
  constexpr size_t R0       = OFF_CN + 8192;               // reusable region start
  constexpr size_t SZ_XB    = (size_t)25216 * 1536 * 2;    // 77,463,552 per bf16 input
  constexpr size_t SZ_A2    = (size_t)LTc * Nc * 1536 * 2; // 101,056,512
  constexpr size_t SZ_WB    = (size_t)2304 * 1536 * 2;     // 7,077,888
  constexpr size_t SZ_WOB   = (size_t)768 * 1536 * 2;      // 2,359,296
  constexpr size_t FULL_NEED = R0 + 3 * SZ_XB + SZ_WB + SZ_WOB;   // ~475.4 MB

  uint8_t* w8 = (uint8_t*)d_ws;
  float* q_ws   = (float*)w8;
  float* k_ws   = (float*)(w8 + SZ_HEADF);
  float* v_ws   = (float*)(w8 + 2 * SZ_HEADF);
  float* center = (float*)(w8 + OFF_CEN);
  float* cnorm  = (float*)(w8 + OFF_CN);
  unsigned short* A2b = (unsigned short*)(w8 + R0);        // lives during attn..gemm2

  const bool full = ws_size >= FULL_NEED;
  unsigned short* wb  = (unsigned short*)(w8 + (full ? (R0 + 3 * SZ_XB) : (R0 + SZ_XB)));
  unsigned short* wob = (unsigned short*)(w8 + (full ? (R0 + 3 * SZ_XB + SZ_WB) : (R0 + SZ_A2)));

  (void)in_sizes; (void)n_in; (void)out_size;

  // weight conversions (tiny)
  convert_hilo<<<(2304 * 192 + 255) / 256, 256, 0, stream>>>(w_in, wb, 2304);
  convert_hilo<<<(768 * 192 + 255) / 256, 256, 0, stream>>>(w_out, wob, 768);

  const int xblk = (25216 * 192 + 255) / 256;
  if (full) {
    unsigned short* xb0 = (unsigned short*)(w8 + R0);
    unsigned short* xb1 = xb0 + SZ_XB / 2;
    unsigned short* xb2 = xb1 + SZ_XB / 2;
    convert_hilo<<<xblk, 256, 0, stream>>>(query, xb0, 25216);
    convert_hilo<<<xblk, 256, 0, stream>>>(key,   xb1, 25216);
    convert_hilo<<<xblk, 256, 0, stream>>>(value, xb2, 25216);
    gemm_mfma<0><<<dim3(197, 18), 256, 0, stream>>>(xb0, xb1, xb2, wb, b_in, 0,
                                                    q_ws, k_ws, v_ws);
  } else {
    unsigned short* buf = (unsigned short*)(w8 + R0);
    const float* xs[3] = {query, key, value};
    for (int wh = 0; wh < 3; wh++) {
      convert_hilo<<<xblk, 256, 0, stream>>>(xs[wh], buf, 25216);
      gemm_mfma<0><<<dim3(197, 6), 256, 0, stream>>>(buf, buf, buf, wb, b_in, 6 * wh,
                                                     q_ws, k_ws, v_ws);
    }
  }

  center_kernel<<<dim3(1536), 256, 0, stream>>>(q_ws, k_ws, center, cnorm);

  // attn_weights accumulated atomically -> zero it (d_out is poisoned 0xAA)
  hipMemsetAsync(attn_w, 0, (size_t)Nc * LTc * Lc * sizeof(float), stream);

  attn_kernel<<<dim3(1536), 512, 0, stream>>>(q_ws, k_ws, v_ws, center, cnorm,
                                              A2b, attn_w);

  gemm_mfma<1><<<dim3(257, 6), 256, 0, stream>>>(A2b, nullptr, nullptr, wob, b_out, 0,
                                                 out, nullptr, nullptr);
}